// Round 5
// baseline (183.814 us; speedup 1.0000x reference)
//
#include <hip/hip_runtime.h>
#include <hip/hip_bf16.h>

// FeatureProcessingBlock: per 64x64 window, Out = sum_t Cs_t^T ( Hs_t^T @ X_c @ Ws_t )
// R5: Y1 fragment-major (A writes B-operand frags directly: writes & reads exact-min
//     bank-balanced), Zb 56B rows (write exact-min), else R4 structure.

typedef __attribute__((ext_vector_type(8))) short short8;
typedef __attribute__((ext_vector_type(4))) short short4v;
typedef __attribute__((ext_vector_type(4))) float float4v;

#define SMEM_BYTES 120336
// Y1F @0: [3t*8c][2 sv][64 lane][16 B] = 49152
// Zb @49152: [1024 px][56 B] (slots k=t*8+cl at byte 2k; 48..55 pad) = 57344
// Cf @106496: [18 ss*m][16 lc][48 B] = 13824 | z16 @120320: 16 B zeros

static __device__ __forceinline__ unsigned short f2bf(float f) {
  return __builtin_bit_cast(unsigned short, __float2bfloat16(f));
}
static __device__ __forceinline__ unsigned long long pk4(float a, float b, float c, float d) {
  unsigned long long lo = (unsigned int)((unsigned int)f2bf(a) | ((unsigned int)f2bf(b) << 16));
  unsigned long long hi = (unsigned int)((unsigned int)f2bf(c) | ((unsigned int)f2bf(d) << 16));
  return lo | (hi << 32);
}

__global__ __launch_bounds__(512, 2)
void fpb5(const float* __restrict__ x, const float* __restrict__ Ws,
          const float* __restrict__ Hsm, const float* __restrict__ Cs,
          float* __restrict__ out) {
  extern __shared__ char smem[];
  char* Y1F = smem;
  char* Zb  = smem + 49152;
  char* Cf  = smem + 106496;
  char* z16 = smem + 120320;

  int wid = (blockIdx.x & 7) * 128 + (blockIdx.x >> 3);  // XCD swizzle
  int window = wid >> 2, tile = wid & 3;
  int b = window >> 6, p = (window >> 3) & 7, q = window & 7;
  int j0 = tile * 16;

  int tid = threadIdx.x, lane = tid & 63, wave = tid >> 6;
  int lq = lane >> 4, lc = lane & 15;
  int mt = wave & 3, cp = wave >> 2;

  if (tid < 4) ((unsigned int*)z16)[tid] = 0;

  // Cf init: row (ss*3+m, lc); slot k = t*8+cl -> lane lq holds t=lq, e=cl
  for (int idx = wave; idx < 18; idx += 8) {
    int ss = idx / 3, m = idx - 3 * ss;
    if (lq < 3) {
      short8 v;
      #pragma unroll
      for (int e = 0; e < 8; ++e)
        v[e] = (short)f2bf(Cs[lq * 2304 + (8 * ss + e) * 48 + 16 * m + lc]);
      *(short8*)(Cf + (idx * 16 + lc) * 48 + lq * 16) = v;
    }
  }

  // persistent factor fragments
  short8 wsf[3][2], hsf[3][2];
  #pragma unroll
  for (int t = 0; t < 3; ++t)
    #pragma unroll
    for (int sv = 0; sv < 2; ++sv) {
      short8 aa, bb;
      #pragma unroll
      for (int e = 0; e < 8; ++e) {
        int k = 32 * sv + 8 * lq + e;
        aa[e] = (short)f2bf(Ws [t * 4096 + k * 64 + j0 + lc]);      // B: Ws[w][W']
        bb[e] = (short)f2bf(Hsm[t * 4096 + k * 64 + 16 * mt + lc]); // A: Hs^T[H'][h]
      }
      wsf[t][sv] = aa; hsf[t][sv] = bb;
    }

  float4v acc[3][8];
  #pragma unroll
  for (int m = 0; m < 3; ++m)
    #pragma unroll
    for (int i = 0; i < 8; ++i) acc[m][i] = float4v{0.f, 0.f, 0.f, 0.f};

  // A-stage: wave = c (within chunk); rows 16*mA+lc, cols 8*lq(+32)
  const float* xbase = x + (((size_t)b * 48) * 512 + p * 64) * 512 + q * 64
                         + (size_t)wave * 262144 + (size_t)lc * 512 + 8 * lq;

  float4v fin[2][8];   // two half-chunk prefetch slots
  #pragma unroll
  for (int h = 0; h < 2; ++h) {
    const float* src = xbase + (size_t)(32 * h) * 512;
    #pragma unroll
    for (int j2 = 0; j2 < 2; ++j2) {
      const float* r = src + (size_t)(16 * j2) * 512;
      fin[h][4*j2+0] = *(const float4v*)(r);
      fin[h][4*j2+1] = *(const float4v*)(r + 4);
      fin[h][4*j2+2] = *(const float4v*)(r + 32);
      fin[h][4*j2+3] = *(const float4v*)(r + 36);
    }
  }

  for (int s = 0; s < 6; ++s) {
    // ---- A: Y1[t][c=wave] = X_c @ Ws_t (contract w); D-frags -> frag-major LDS ----
    #pragma unroll
    for (int h = 0; h < 2; ++h) {
      short8 af[4];
      #pragma unroll
      for (int j2 = 0; j2 < 2; ++j2) {
        short8 a0, a1;
        #pragma unroll
        for (int e2 = 0; e2 < 4; ++e2) {
          a0[e2]   = (short)f2bf(fin[h][4*j2+0][e2]);
          a0[4+e2] = (short)f2bf(fin[h][4*j2+1][e2]);
          a1[e2]   = (short)f2bf(fin[h][4*j2+2][e2]);
          a1[4+e2] = (short)f2bf(fin[h][4*j2+3][e2]);
        }
        af[2*j2] = a0; af[2*j2+1] = a1;
      }
      if (s < 5) {  // refill this slot for chunk s+1
        const float* src = xbase + (size_t)(s + 1) * 2097152 + (size_t)(32 * h) * 512;
        #pragma unroll
        for (int j2 = 0; j2 < 2; ++j2) {
          const float* r = src + (size_t)(16 * j2) * 512;
          fin[h][4*j2+0] = *(const float4v*)(r);
          fin[h][4*j2+1] = *(const float4v*)(r + 4);
          fin[h][4*j2+2] = *(const float4v*)(r + 32);
          fin[h][4*j2+3] = *(const float4v*)(r + 36);
        }
      }
      #pragma unroll
      for (int j2 = 0; j2 < 2; ++j2) {
        int mA = 2 * h + j2;
        int sv  = mA >> 1;
        int lqp = (2 * mA + (lq >> 1)) & 3;          // B-frag lane group for rows h
        int eo  = (lq & 1) * 8;                      // byte offset of e=4*(lq&1)
        #pragma unroll
        for (int t = 0; t < 3; ++t) {
          float4v d = {0.f, 0.f, 0.f, 0.f};
          d = __builtin_amdgcn_mfma_f32_16x16x32_bf16(af[2*j2],   wsf[t][0], d, 0, 0, 0);
          d = __builtin_amdgcn_mfma_f32_16x16x32_bf16(af[2*j2+1], wsf[t][1], d, 0, 0, 0);
          short4v pv;
          pv[0] = (short)f2bf(d[0]); pv[1] = (short)f2bf(d[1]);
          pv[2] = (short)f2bf(d[2]); pv[3] = (short)f2bf(d[3]);
          *(short4v*)(Y1F + ((t * 8 + wave) * 2 + sv) * 1024
                          + (lqp * 16 + lc) * 16 + eo) = pv;
        }
      }
    }
    __syncthreads();

    // ---- B: Zb[px][k=t*8+cl] = Hs_t^T @ Y1 (contract h); linear frag reads ----
    #pragma unroll
    for (int t = 0; t < 3; ++t) {
      float4v dB[4];
      #pragma unroll
      for (int cj = 0; cj < 4; ++cj) {
        const char* yb = Y1F + ((t * 8 + 4 * cp + cj) * 2) * 1024 + lane * 16;
        short8 y0 = *(const short8*)yb;
        short8 y1 = *(const short8*)(yb + 1024);
        float4v dd = {0.f, 0.f, 0.f, 0.f};
        dd = __builtin_amdgcn_mfma_f32_16x16x32_bf16(hsf[t][0], y0, dd, 0, 0, 0);
        dd = __builtin_amdgcn_mfma_f32_16x16x32_bf16(hsf[t][1], y1, dd, 0, 0, 0);
        dB[cj] = dd;
      }
      #pragma unroll
      for (int r = 0; r < 4; ++r) {
        int px = (16 * mt + 4 * lq + r) * 16 + lc;
        *(unsigned long long*)(Zb + px * 56 + 16 * t + 8 * cp) =
            pk4(dB[0][r], dB[1][r], dB[2][r], dB[3][r]);
      }
    }
    __syncthreads();

    // ---- C: acc += Cs-frag @ Zb (contract t,c; K=32, slots 24..31 zero) ----
    {
      short8 cf[3];
      #pragma unroll
      for (int m = 0; m < 3; ++m) {
        const char* csrc = (lq < 3) ? (Cf + ((s * 3 + m) * 16 + lc) * 48 + lq * 16) : z16;
        cf[m] = *(const short8*)csrc;
      }
      #pragma unroll
      for (int i = 0; i < 8; ++i) {
        int px = 16 * (wave + 8 * i) + lc;
        const char* zsrc = (lq < 3) ? (Zb + px * 56 + 16 * lq) : z16;
        short8 zf = *(const short8*)zsrc;
        acc[0][i] = __builtin_amdgcn_mfma_f32_16x16x32_bf16(cf[0], zf, acc[0][i], 0, 0, 0);
        acc[1][i] = __builtin_amdgcn_mfma_f32_16x16x32_bf16(cf[1], zf, acc[1][i], 0, 0, 0);
        acc[2][i] = __builtin_amdgcn_mfma_f32_16x16x32_bf16(cf[2], zf, acc[2][i], 0, 0, 0);
      }
    }
    // no barrier: next A writes Y1F (B of next chunk reads after bar1);
    // C's Zb reads complete before next bar1 orders next B's Zb writes.
  }

  // ---- epilogue: fully static stores ----
  #pragma unroll
  for (int m = 0; m < 3; ++m)
    #pragma unroll
    for (int i = 0; i < 8; ++i) {
      int n = wave + 8 * i;
      size_t rowbase = (((size_t)(b * 48 + 16 * m + 4 * lq)) * 512 + p * 64 + n) * 512
                       + q * 64 + j0 + lc;
      #pragma unroll
      for (int r = 0; r < 4; ++r)
        out[rowbase + (size_t)r * 262144] = acc[m][i][r];
    }
}

extern "C" void kernel_launch(void* const* d_in, const int* in_sizes, int n_in,
                              void* d_out, int out_size, void* d_ws, size_t ws_size,
                              hipStream_t stream) {
  (void)in_sizes; (void)n_in; (void)d_ws; (void)ws_size; (void)out_size;
  const float* x   = (const float*)d_in[0];
  const float* Ws  = (const float*)d_in[1];
  const float* Hsm = (const float*)d_in[2];
  const float* Cs  = (const float*)d_in[3];
  float* out = (float*)d_out;
  (void)hipFuncSetAttribute((const void*)fpb5,
                            hipFuncAttributeMaxDynamicSharedMemorySize, SMEM_BYTES);
  fpb5<<<dim3(1024), dim3(512), SMEM_BYTES, stream>>>(x, Ws, Hsm, Cs, out);
}